// Round 1
// 706.049 us; speedup vs baseline: 1.1023x; 1.1023x over previous
//
#include <hip/hip_runtime.h>
#include <stdint.h>

#define N_NODES 50000
#define N_EDGES 800000
#define B_GRAPHS 64
#define D_DIM 64
#define HD 128
#define G_GAUSS 50
#define HID_DIM 128
#define L_LAYERS 3
#define LN2 0.69314718055994530942f
#define PI_OVER_8 0.39269908169872414f
#define NCHUNK 196            // ceil(50000/256)

#define TN 64                 // nodes per node-GEMM block
#define TLD 132               // fp32 LDS leading dim for 128-wide tiles
#define XLD 68                // fp32 LDS leading dim for 64-wide tiles
#define NBLK ((N_NODES + TN - 1) / TN)   // 782

// filter-net lookup table: w(r)*C(r) over r in [0,8), linear interpolation.
// LUT_T=2048 -> lerp error ~7e-5 on gs, far below the bf16 storage error.
#define LUT_T 2048
#define LUT_INV_STEP 256.0f   // LUT_T / 8.0
#define LROWS 8               // table rows built per block

__device__ __forceinline__ float sspf(float x) {
    float ax = fabsf(x);
    return fmaxf(x, 0.f) + __logf(1.f + __expf(-ax)) - LN2;
}
__device__ __forceinline__ unsigned short f2bf(float f) {
    union { float f; unsigned int i; } v; v.f = f;
    unsigned int u = v.i;
    return (unsigned short)((u + 0x7FFFu + ((u >> 16) & 1u)) >> 16);
}

// ------------- one-time: zero counters + zero output -------------
__global__ void repr_prep(int* __restrict__ count_f, int* __restrict__ count_s,
                          float* __restrict__ dout) {
    int i = blockIdx.x * 256 + threadIdx.x;
    if (i < N_NODES) count_f[i] = 0;
    else if (i < 2 * N_NODES) count_s[i - N_NODES] = 0;
    else if (i < 2 * N_NODES + B_GRAPHS) dout[i - 2 * N_NODES] = 0.f;
}

// ------------- one-time: build wc(r) = (ssp(gs@W1+b1)@W2 + b2) * C(r) table -------------
// interleaved bf16: lut[l][i][c] = bf16(wc[i][c]) | bf16(wc[i+1][c])<<16
// built in fp32 with accurate expf/cosf; one uint load per (edge,col) at use time.
__global__ __launch_bounds__(256) void repr_lut_build(
    const float* __restrict__ offs, const float* __restrict__ widths,
    const float* __restrict__ fw1, const float* __restrict__ fb1,
    const float* __restrict__ fw2, const float* __restrict__ fb2,
    unsigned int* __restrict__ lut)
{
    __shared__ float gs_s[LROWS + 1][G_GAUSS];
    __shared__ float hid_s[LROWS + 1][HID_DIM];
    __shared__ float wc_s[LROWS + 1][HD];
    const int nb = LUT_T / LROWS;            // 256 blocks per layer
    int l = blockIdx.x / nb;
    int i0r = (blockIdx.x % nb) * LROWS;
    int tid = threadIdx.x;
    const float step = 8.0f / LUT_T;

    for (int j = tid; j < (LROWS + 1) * G_GAUSS; j += 256) {
        int r = j / G_GAUSS, k = j - r * G_GAUSS;
        float rr = (i0r + r) * step;
        float wdt = widths[k];
        float dr = rr - offs[k];
        gs_s[r][k] = expf(-0.5f / (wdt * wdt) * dr * dr);
    }
    __syncthreads();

    int c = tid & 127, sub = tid >> 7;
    int rlo = sub * 4;                       // rows 0..4 / 4..8 (row 4 dup, benign)
    {
        const float* W1 = fw1 + (size_t)l * G_GAUSS * HID_DIM + c;
        float acc[5];
        float bb = fb1[l * HID_DIM + c];
        #pragma unroll
        for (int r = 0; r < 5; r++) acc[r] = bb;
        for (int k = 0; k < G_GAUSS; k++) {
            float wv = W1[k * HID_DIM];
            #pragma unroll
            for (int r = 0; r < 5; r++)
                acc[r] = fmaf(gs_s[rlo + r][k], wv, acc[r]);
        }
        #pragma unroll
        for (int r = 0; r < 5; r++) hid_s[rlo + r][c] = sspf(acc[r]);
    }
    __syncthreads();
    {
        const float* W2 = fw2 + (size_t)l * HID_DIM * HD + c;
        float acc[5];
        float bb = fb2[l * HD + c];
        #pragma unroll
        for (int r = 0; r < 5; r++) acc[r] = bb;
        for (int k = 0; k < HID_DIM; k++) {
            float wv = W2[k * HD];
            #pragma unroll
            for (int r = 0; r < 5; r++)
                acc[r] = fmaf(hid_s[rlo + r][k], wv, acc[r]);
        }
        #pragma unroll
        for (int r = 0; r < 5; r++) {
            float rr = (i0r + rlo + r) * step;
            float C = (rr < 8.0f) ? 0.5f * (cosf(rr * PI_OVER_8) + 1.f) : 0.f;
            wc_s[rlo + r][c] = acc[r] * C;
        }
    }
    __syncthreads();
    for (int j = tid; j < LROWS * HD; j += 256) {
        int r = j >> 7, cc = j & 127;
        unsigned int lo = f2bf(wc_s[r][cc]);
        unsigned int hi = f2bf(wc_s[r + 1][cc]);
        lut[((size_t)l * LUT_T + i0r + r) * HD + cc] = lo | (hi << 16);
    }
}

// ------------- histograms (+ store r per edge) -------------
__global__ void repr_hist(const float* __restrict__ R,
                          const int* __restrict__ src, const int* __restrict__ dst,
                          int* __restrict__ count_f, int* __restrict__ count_s,
                          float* __restrict__ r_full) {
    int e = blockIdx.x * blockDim.x + threadIdx.x;
    if (e >= N_EDGES) return;
    int s = src[e], d = dst[e];
    atomicAdd(&count_f[d], 1);
    float dx = R[3*s+0] - R[3*d+0];
    float dy = R[3*s+1] - R[3*d+1];
    float dz = R[3*s+2] - R[3*d+2];
    float r = sqrtf(dx*dx + dy*dy + dz*dz);
    r_full[e] = r;
    if (r < 8.0f) atomicAdd(&count_s[d], 1);
}

// ------------- dual 2-level exclusive scan over 50000 counts -------------
__global__ void repr_scanA2(const int* __restrict__ cntA, int* __restrict__ exclA,
                            int* __restrict__ bsumA,
                            const int* __restrict__ cntB, int* __restrict__ exclB,
                            int* __restrict__ bsumB) {
    __shared__ int tmp[256];
    int t = threadIdx.x, b = blockIdx.x;
    const int* cnt; int* excl; int* bsum; int bb;
    if (b < NCHUNK) { cnt = cntA; excl = exclA; bsum = bsumA; bb = b; }
    else            { cnt = cntB; excl = exclB; bsum = bsumB; bb = b - NCHUNK; }
    int i = bb * 256 + t;
    int v = (i < N_NODES) ? cnt[i] : 0;
    tmp[t] = v; __syncthreads();
    for (int off = 1; off < 256; off <<= 1) {
        int add = (t >= off) ? tmp[t - off] : 0;
        __syncthreads();
        tmp[t] += add;
        __syncthreads();
    }
    if (i < N_NODES) excl[i] = tmp[t] - v;
    if (t == 255) bsum[bb] = tmp[255];
}
__global__ void repr_scanB2(const int* __restrict__ bsumA, int* __restrict__ bprefA,
                            int* __restrict__ ecA,
                            const int* __restrict__ bsumB, int* __restrict__ bprefB,
                            int* __restrict__ ecB) {
    __shared__ int tmp[256];
    const int* bsum = blockIdx.x ? bsumB : bsumA;
    int* bpref = blockIdx.x ? bprefB : bprefA;
    int* ec = blockIdx.x ? ecB : ecA;
    int t = threadIdx.x;
    int v = (t < NCHUNK) ? bsum[t] : 0;
    tmp[t] = v; __syncthreads();
    for (int off = 1; off < 256; off <<= 1) {
        int add = (t >= off) ? tmp[t - off] : 0;
        __syncthreads();
        tmp[t] += add;
        __syncthreads();
    }
    if (t < NCHUNK) bpref[t] = tmp[t] - v;
    if (t == 255) ec[0] = tmp[255];
}
__global__ void repr_scanC2(const int* __restrict__ exclA, const int* __restrict__ bprefA,
                            int* __restrict__ curA, int* __restrict__ rowptr,
                            const int* __restrict__ exclB, const int* __restrict__ bprefB,
                            int* __restrict__ curB) {
    int b = blockIdx.x;
    if (b < NCHUNK) {
        int i = b * 256 + threadIdx.x;
        if (i < N_NODES) { int v = exclA[i] + bprefA[b]; curA[i] = v; rowptr[i] = v; }
    } else {
        int i = (b - NCHUNK) * 256 + threadIdx.x;
        if (i < N_NODES) curB[i] = exclB[i] + bprefB[b - NCHUNK];
    }
}

// ------------- scatter: full dst-sorted list + survivor dst-sorted list -------------
__global__ void repr_scatter(const float* __restrict__ r_full,
                             const int* __restrict__ src, const int* __restrict__ dst,
                             int* __restrict__ cur_f, int* __restrict__ cur_s,
                             int* __restrict__ ssrc_f, int* __restrict__ sdst_f,
                             int* __restrict__ ssrc2, int* __restrict__ sdst2,
                             float* __restrict__ r2) {
    int e = blockIdx.x * blockDim.x + threadIdx.x;
    if (e >= N_EDGES) return;
    int s = src[e], d = dst[e];
    float r = r_full[e];
    int pos = atomicAdd(&cur_f[d], 1);
    ssrc_f[pos] = s; sdst_f[pos] = d;
    if (r < 8.0f) {
        int p2 = atomicAdd(&cur_s[d], 1);
        ssrc2[p2] = s; sdst2[p2] = d; r2[p2] = r;
    }
}

// ================= tiled fp32 node GEMMs (64 nodes / block, 256 threads) =================

__device__ __forceinline__ void load_ssp_agg(int base, int tid,
        const float* __restrict__ agg, float* __restrict__ bufA) {
    int row = tid >> 2;
    int c0 = (tid & 3) << 5;
    const float* ap = agg + (size_t)(base + row) * HD + c0;
    float* tp = bufA + row * TLD + c0;
    #pragma unroll
    for (int j = 0; j < 8; j++) {
        float4 v = *(const float4*)(ap + j * 4);
        tp[j*4+0] = sspf(v.x); tp[j*4+1] = sspf(v.y);
        tp[j*4+2] = sspf(v.z); tp[j*4+3] = sspf(v.w);
    }
}

__device__ __forceinline__ void gemm_mlp(int base, int tid,
        const float* __restrict__ w1, const float* __restrict__ b1,
        const float* __restrict__ w2, const float* __restrict__ b2,
        float* __restrict__ x, float* __restrict__ bufA, float* __restrict__ v1s)
{
    const int rg = tid >> 4, cg = tid & 15;
    const int r0 = rg * 4, c0 = cg * 4;
    float acc[4][4];
    #pragma unroll
    for (int r = 0; r < 4; r++)
        #pragma unroll
        for (int c = 0; c < 4; c++) acc[r][c] = 0.f;
    for (int k0 = 0; k0 < 128; k0 += 4) {
        float av[4][4];
        #pragma unroll
        for (int r = 0; r < 4; r++)
            *(float4*)av[r] = *(const float4*)&bufA[(r0 + r) * TLD + k0];
        #pragma unroll
        for (int kk = 0; kk < 4; kk++) {
            float4 wv = *(const float4*)(w1 + (k0 + kk) * 64 + c0);
            float wf[4] = {wv.x, wv.y, wv.z, wv.w};
            #pragma unroll
            for (int r = 0; r < 4; r++)
                #pragma unroll
                for (int c = 0; c < 4; c++)
                    acc[r][c] = fmaf(av[r][kk], wf[c], acc[r][c]);
        }
    }
    {
        float4 bv = *(const float4*)(b1 + c0);
        float ba[4] = {bv.x, bv.y, bv.z, bv.w};
        #pragma unroll
        for (int r = 0; r < 4; r++)
            #pragma unroll
            for (int c = 0; c < 4; c++)
                v1s[(r0 + r) * XLD + c0 + c] = sspf(acc[r][c] + ba[c]);
    }
    __syncthreads();
    float acc2[4][4];
    #pragma unroll
    for (int r = 0; r < 4; r++)
        #pragma unroll
        for (int c = 0; c < 4; c++) acc2[r][c] = 0.f;
    for (int k0 = 0; k0 < 64; k0 += 4) {
        float av[4][4];
        #pragma unroll
        for (int r = 0; r < 4; r++)
            *(float4*)av[r] = *(const float4*)&v1s[(r0 + r) * XLD + k0];
        #pragma unroll
        for (int kk = 0; kk < 4; kk++) {
            float4 wv = *(const float4*)(w2 + (k0 + kk) * 64 + c0);
            float wf[4] = {wv.x, wv.y, wv.z, wv.w};
            #pragma unroll
            for (int r = 0; r < 4; r++)
                #pragma unroll
                for (int c = 0; c < 4; c++)
                    acc2[r][c] = fmaf(av[r][kk], wf[c], acc2[r][c]);
        }
    }
    {
        float4 bv = *(const float4*)(b2 + c0);
        #pragma unroll
        for (int r = 0; r < 4; r++) {
            int n = base + r0 + r;
            float4 xv = *(const float4*)(x + (size_t)n * 64 + c0);
            float4 o;
            o.x = acc2[r][0] + bv.x + xv.x;
            o.y = acc2[r][1] + bv.y + xv.y;
            o.z = acc2[r][2] + bv.z + xv.z;
            o.w = acc2[r][3] + bv.w + xv.w;
            *(float4*)&bufA[(r0 + r) * XLD + c0] = o;
            if (n < N_NODES) *(float4*)(x + (size_t)n * 64 + c0) = o;
        }
    }
    __syncthreads();
}

__device__ __forceinline__ void gemm_h(int base, int tid,
        const float* __restrict__ bufA,
        const float* __restrict__ fc_w, const float* __restrict__ attn_l,
        const float* __restrict__ attn_r,
        float* __restrict__ h, float* __restrict__ el, float* __restrict__ er)
{
    const int rg = tid >> 4, cg = tid & 15;
    const int r0 = rg * 4, c0 = cg * 8;
    float acc[4][8];
    #pragma unroll
    for (int r = 0; r < 4; r++)
        #pragma unroll
        for (int c = 0; c < 8; c++) acc[r][c] = 0.f;
    for (int k0 = 0; k0 < 64; k0 += 4) {
        float av[4][4];
        #pragma unroll
        for (int r = 0; r < 4; r++)
            *(float4*)av[r] = *(const float4*)&bufA[(r0 + r) * XLD + k0];
        #pragma unroll
        for (int kk = 0; kk < 4; kk++) {
            float4 w0 = *(const float4*)(fc_w + (k0 + kk) * 128 + c0);
            float4 w1v = *(const float4*)(fc_w + (k0 + kk) * 128 + c0 + 4);
            float wf[8] = {w0.x, w0.y, w0.z, w0.w, w1v.x, w1v.y, w1v.z, w1v.w};
            #pragma unroll
            for (int r = 0; r < 4; r++)
                #pragma unroll
                for (int c = 0; c < 8; c++)
                    acc[r][c] = fmaf(av[r][kk], wf[c], acc[r][c]);
        }
    }
    float al[8], ar[8];
    #pragma unroll
    for (int c = 0; c < 8; c++) { al[c] = attn_l[c0 + c]; ar[c] = attn_r[c0 + c]; }
    int head = cg >> 3;
    #pragma unroll
    for (int r = 0; r < 4; r++) {
        int n = base + r0 + r;
        float pel = 0.f, per = 0.f;
        #pragma unroll
        for (int c = 0; c < 8; c++) {
            pel = fmaf(acc[r][c], al[c], pel);
            per = fmaf(acc[r][c], ar[c], per);
        }
        if (n < N_NODES) {
            float4 lo = {acc[r][0], acc[r][1], acc[r][2], acc[r][3]};
            float4 hi = {acc[r][4], acc[r][5], acc[r][6], acc[r][7]};
            *(float4*)(h + (size_t)n * HD + c0) = lo;
            *(float4*)(h + (size_t)n * HD + c0 + 4) = hi;
        }
        #pragma unroll
        for (int off = 1; off < 8; off <<= 1) {
            pel += __shfl_xor(pel, off, 64);
            per += __shfl_xor(per, off, 64);
        }
        if ((cg & 7) == 0 && n < N_NODES) {
            el[n * 2 + head] = pel;
            er[n * 2 + head] = per;
        }
    }
}

__global__ __launch_bounds__(256) void repr_embed_h(
        const float* __restrict__ emb, const int* __restrict__ Z,
        const float* __restrict__ fc_w, const float* __restrict__ attn_l,
        const float* __restrict__ attn_r,
        float* __restrict__ x, float* __restrict__ h,
        float* __restrict__ el, float* __restrict__ er) {
    __shared__ float bufA[TN * XLD];
    int base = blockIdx.x * TN, tid = threadIdx.x;
    int row = tid >> 2;
    int c0 = (tid & 3) << 4;
    int n = base + row;
    int z = (n < N_NODES) ? Z[n] : 0;
    const float* ep = emb + (size_t)z * D_DIM + c0;
    float* bp = bufA + row * XLD + c0;
    #pragma unroll
    for (int j = 0; j < 4; j++) {
        float4 v = *(const float4*)(ep + j * 4);
        *(float4*)(bp + j * 4) = v;
        if (n < N_NODES) *(float4*)(x + (size_t)n * D_DIM + c0 + j * 4) = v;
    }
    __syncthreads();
    gemm_h(base, tid, bufA, fc_w, attn_l, attn_r, h, el, er);
}

__global__ __launch_bounds__(256) void repr_mlp_h(
        const float* __restrict__ agg,
        const float* __restrict__ w1, const float* __restrict__ b1,
        const float* __restrict__ w2, const float* __restrict__ b2,
        const float* __restrict__ fc_w, const float* __restrict__ attn_l,
        const float* __restrict__ attn_r,
        float* __restrict__ x, float* __restrict__ h,
        float* __restrict__ el, float* __restrict__ er) {
    __shared__ float bufA[TN * TLD];
    __shared__ float v1s[TN * XLD];
    int base = blockIdx.x * TN, tid = threadIdx.x;
    load_ssp_agg(base, tid, agg, bufA);
    __syncthreads();
    gemm_mlp(base, tid, w1, b1, w2, b2, x, bufA, v1s);
    gemm_h(base, tid, bufA, fc_w, attn_l, attn_r, h, el, er);
}

__global__ __launch_bounds__(256) void repr_mlp_out(
        const float* __restrict__ agg,
        const float* __restrict__ w1, const float* __restrict__ b1,
        const float* __restrict__ w2, const float* __restrict__ b2,
        const float* __restrict__ ow1, const float* __restrict__ ob1,
        const float* __restrict__ ow2, const float* __restrict__ ob2,
        float* __restrict__ x, float* __restrict__ hh) {
    __shared__ float bufA[TN * TLD];
    __shared__ float v1s[TN * XLD];
    int base = blockIdx.x * TN, tid = threadIdx.x;
    load_ssp_agg(base, tid, agg, bufA);
    __syncthreads();
    gemm_mlp(base, tid, w1, b1, w2, b2, x, bufA, v1s);
    const int rg = tid >> 4, cg = tid & 15;
    const int r0 = rg * 4, c0 = cg * 8;
    float acc[4][8];
    #pragma unroll
    for (int r = 0; r < 4; r++)
        #pragma unroll
        for (int c = 0; c < 8; c++) acc[r][c] = 0.f;
    for (int k0 = 0; k0 < 64; k0 += 4) {
        float av[4][4];
        #pragma unroll
        for (int r = 0; r < 4; r++)
            *(float4*)av[r] = *(const float4*)&bufA[(r0 + r) * XLD + k0];
        #pragma unroll
        for (int kk = 0; kk < 4; kk++) {
            float4 w0 = *(const float4*)(ow1 + (k0 + kk) * 128 + c0);
            float4 w1v = *(const float4*)(ow1 + (k0 + kk) * 128 + c0 + 4);
            float wf[8] = {w0.x, w0.y, w0.z, w0.w, w1v.x, w1v.y, w1v.z, w1v.w};
            #pragma unroll
            for (int r = 0; r < 4; r++)
                #pragma unroll
                for (int c = 0; c < 8; c++)
                    acc[r][c] = fmaf(av[r][kk], wf[c], acc[r][c]);
        }
    }
    float o1[8], w2c[8];
    #pragma unroll
    for (int c = 0; c < 8; c++) { o1[c] = ob1[c0 + c]; w2c[c] = ow2[c0 + c]; }
    #pragma unroll
    for (int r = 0; r < 4; r++) {
        int n = base + r0 + r;
        float s = 0.f;
        #pragma unroll
        for (int c = 0; c < 8; c++)
            s = fmaf(sspf(acc[r][c] + o1[c]), w2c[c], s);
        #pragma unroll
        for (int off = 1; off < 16; off <<= 1)
            s += __shfl_xor(s, off, 64);
        if (cg == 0 && n < N_NODES) hh[n] = s + ob2[0];
    }
}

// ------------- softmax denominators (no max subtraction) + agg zeroing -------------
__global__ void repr_alpha(const int* __restrict__ ssrc_f, const int* __restrict__ rowptr,
                           const float* __restrict__ el, const float* __restrict__ er,
                           float2* __restrict__ md, float* __restrict__ agg) {
    int t = blockIdx.x * 256 + threadIdx.x;
    int d = t >> 4;
    int lane16 = t & 15;
    if (d >= N_NODES) return;
    float4 z = make_float4(0.f, 0.f, 0.f, 0.f);
    float4* ar = (float4*)(agg + (size_t)d * HD);
    ar[lane16 * 2] = z;
    ar[lane16 * 2 + 1] = z;
    int rs = rowptr[d];
    int re = (d == N_NODES - 1) ? N_EDGES : rowptr[d + 1];
    float2 erd = *(const float2*)&er[2 * d];
    float s0 = 0.f, s1 = 0.f;
    for (int i = rs + lane16; i < re; i += 16) {
        int s = ssrc_f[i];
        float2 a = *(const float2*)&el[2 * s];
        float v0 = a.x + erd.x; v0 = v0 >= 0.f ? v0 : 0.2f * v0;
        float v1 = a.y + erd.y; v1 = v1 >= 0.f ? v1 : 0.2f * v1;
        s0 += __expf(v0);
        s1 += __expf(v1);
    }
    #pragma unroll
    for (int off = 8; off > 0; off >>= 1) {
        s0 += __shfl_xor(s0, off, 64);
        s1 += __shfl_xor(s1, off, 64);
    }
    if (lane16 == 0) md[d] = make_float2(1.f / s0, 1.f / s1);
}

// ------------- LUT-based message + segmented-reduce scatter -------------
// Replaces the MFMA filter-net: per edge, lerp wc(r) from the bf16 interleaved
// table (one uint load covers both lerp rows), multiply by h[src] and the
// per-(edge,head) alpha scale, accumulate segmented sums directly in registers.
// 256 threads = 128 cols x 2 row-subranges of 32 edges each.
#define TILE 64
__global__ __launch_bounds__(256) void repr_msg_lut(
    const int* __restrict__ ssrc2, const int* __restrict__ sdst2,
    const float* __restrict__ r2, const int* __restrict__ ecount,
    const float* __restrict__ el, const float* __restrict__ er,
    const float2* __restrict__ md, const float* __restrict__ h,
    const unsigned int* __restrict__ lut,
    float* __restrict__ agg)
{
    __shared__ int4 rowinfo[TILE];     // {lut row i0, src, dst, frac bits}
    __shared__ float scl[TILE][2];
    int EC = ecount[0];
    int base = blockIdx.x * TILE;
    if (base >= EC) return;
    int tid = threadIdx.x;
    if (tid < TILE) {
        int i = base + tid;
        int sn = 0, d = -1, i0 = 0;
        float fr = 0.f, sc0 = 0.f, sc1 = 0.f;
        if (i < EC) {
            sn = ssrc2[i]; d = sdst2[i];
            float t = r2[i] * LUT_INV_STEP;
            i0 = (int)t;
            if (i0 > LUT_T - 1) i0 = LUT_T - 1;
            fr = t - (float)i0;
            float2 a = *(const float2*)&el[2 * sn];
            float2 b = *(const float2*)&er[2 * d];
            float2 rd = md[d];
            float v0 = a.x + b.x; v0 = v0 >= 0.f ? v0 : 0.2f * v0;
            float v1 = a.y + b.y; v1 = v1 >= 0.f ? v1 : 0.2f * v1;
            sc0 = __expf(v0) * rd.x;       // C(r) is folded into the table
            sc1 = __expf(v1) * rd.y;
        }
        rowinfo[tid] = make_int4(i0, sn, d, __float_as_int(fr));
        scl[tid][0] = sc0; scl[tid][1] = sc1;
    }
    __syncthreads();
    const int col = tid & 127;
    const int sp = tid >> 7;           // row-subrange: rows [sp*32, sp*32+32)
    const int head = col >> 6;         // wave-uniform
    const int lo = sp * 32;
    const unsigned int* __restrict__ lc = lut + col;
    const float* __restrict__ hc = h + col;
    float sum = 0.f;
    int cur_d = -1;
    int seg_first = 1;                 // current segment started at subrange begin
    #pragma unroll 4
    for (int j = 0; j < 32; j++) {
        int r = lo + j;
        int4 ri = rowinfo[r];          // wave-uniform LDS broadcast
        if (ri.z != cur_d) {
            if (cur_d >= 0) {
                float* ap = &agg[(size_t)cur_d * HD + col];
                // segment possibly extends into previous subrange/block -> atomic
                if (seg_first) atomicAdd(ap, sum); else *ap = sum;
            }
            cur_d = ri.z; sum = 0.f; seg_first = (j == 0);
        }
        if (ri.z >= 0) {
            unsigned int tv = lc[(size_t)ri.x * HD];
            float w0 = __uint_as_float(tv << 16);          // bf16 row i0
            float w1 = __uint_as_float(tv & 0xFFFF0000u);  // bf16 row i0+1
            float wv = fmaf(__int_as_float(ri.w), w1 - w0, w0);
            float hv = hc[(size_t)ri.y * HD];
            sum = fmaf(wv * hv, scl[r][head], sum);
        }
    }
    // trailing segment may continue into next subrange/block -> atomic
    if (cur_d >= 0)
        atomicAdd(&agg[(size_t)cur_d * HD + col], sum);
}

// ------------- graph segment-sum with LDS privatization -> d_out directly -------------
__global__ void repr_gsum(const float* __restrict__ hh, const int* __restrict__ gids,
                          float* __restrict__ dout) {
    __shared__ float bins[B_GRAPHS];
    int t = threadIdx.x;
    if (t < B_GRAPHS) bins[t] = 0.f;
    __syncthreads();
    int i = blockIdx.x * 256 + t;
    if (i < N_NODES) atomicAdd(&bins[gids[i]], hh[i]);
    __syncthreads();
    if (t < B_GRAPHS && bins[t] != 0.f) atomicAdd(&dout[t], bins[t]);
}

extern "C" void kernel_launch(void* const* d_in, const int* in_sizes, int n_in,
                              void* d_out, int out_size, void* d_ws, size_t ws_size,
                              hipStream_t stream) {
    (void)in_sizes; (void)n_in; (void)out_size; (void)ws_size;
    const float* R      = (const float*)d_in[0];
    const int*   Z      = (const int*)d_in[1];
    const int*   src    = (const int*)d_in[2];
    const int*   dst    = (const int*)d_in[3];
    const int*   gids   = (const int*)d_in[4];
    const float* emb    = (const float*)d_in[5];
    const float* offs   = (const float*)d_in[6];
    const float* widths = (const float*)d_in[7];
    const float* fc_w   = (const float*)d_in[8];
    const float* attn_l = (const float*)d_in[9];
    const float* attn_r = (const float*)d_in[10];
    const float* fw1    = (const float*)d_in[11];
    const float* fb1    = (const float*)d_in[12];
    const float* fw2    = (const float*)d_in[13];
    const float* fb2    = (const float*)d_in[14];
    const float* mw1    = (const float*)d_in[15];
    const float* mb1    = (const float*)d_in[16];
    const float* mw2    = (const float*)d_in[17];
    const float* mb2    = (const float*)d_in[18];
    const float* ow1    = (const float*)d_in[19];
    const float* ob1    = (const float*)d_in[20];
    const float* ow2    = (const float*)d_in[21];
    const float* ob2    = (const float*)d_in[22];

    char* p = (char*)d_ws;
    float* x      = (float*)p; p += (size_t)N_NODES * 64 * 4;
    float* h      = (float*)p; p += (size_t)N_NODES * 128 * 4;
    float* el     = (float*)p; p += (size_t)N_NODES * 2 * 4;
    float* er     = (float*)p; p += (size_t)N_NODES * 2 * 4;
    float2* md    = (float2*)p; p += (size_t)N_NODES * 8;
    float* agg    = (float*)p; p += (size_t)N_NODES * 128 * 4;
    int*   ssrc_f = (int*)p;   p += (size_t)N_EDGES * 4;
    int*   sdst_f = (int*)p;   p += (size_t)N_EDGES * 4;
    int*   rowptr = (int*)p;   p += (size_t)N_NODES * 4;
    int*   ssrc2  = (int*)p;   p += (size_t)N_EDGES * 4;
    int*   sdst2  = (int*)p;   p += (size_t)N_EDGES * 4;
    float* r2     = (float*)p; p += (size_t)N_EDGES * 4;
    float* r_full = (float*)p; p += (size_t)N_EDGES * 4;
    float* hh     = (float*)p; p += (size_t)N_NODES * 4;
    int*   bsumA  = (int*)p;   p += 1024;
    int*   bprefA = (int*)p;   p += 1024;
    int*   bsumB  = (int*)p;   p += 1024;
    int*   bprefB = (int*)p;   p += 1024;
    int*   ecF    = (int*)p;   p += 256;
    int*   ecS    = (int*)p;   p += 256;
    // filter-net LUT aliases r_full: 3*2048*128*4 = 3,145,728 B <= 3,200,000 B.
    // r_full is dead after repr_scatter; lut is built strictly after it.
    unsigned int* lut = (unsigned int*)r_full;
    // scan temporaries aliased into x (x written by repr_embed_h, strictly after
    // repr_scatter in stream order):
    int* count_f = (int*)x;
    int* excl_f  = (int*)((char*)x + 256 * 1024);
    int* cur_f   = (int*)((char*)x + 512 * 1024);
    int* count_s = (int*)((char*)x + 768 * 1024);
    int* excl_s  = (int*)((char*)x + 1024 * 1024);
    int* cur_s   = (int*)((char*)x + 1280 * 1024);

    // one-time prep: zero counters + zero d_out
    repr_prep<<<(2 * N_NODES + B_GRAPHS + 255) / 256, 256, 0, stream>>>(
        count_f, count_s, (float*)d_out);
    repr_hist<<<N_EDGES / 256, 256, 0, stream>>>(R, src, dst, count_f, count_s, r_full);
    repr_scanA2<<<2 * NCHUNK, 256, 0, stream>>>(count_f, excl_f, bsumA,
                                                count_s, excl_s, bsumB);
    repr_scanB2<<<2, 256, 0, stream>>>(bsumA, bprefA, ecF, bsumB, bprefB, ecS);
    repr_scanC2<<<2 * NCHUNK, 256, 0, stream>>>(excl_f, bprefA, cur_f, rowptr,
                                                excl_s, bprefB, cur_s);
    repr_scatter<<<N_EDGES / 256, 256, 0, stream>>>(
        r_full, src, dst, cur_f, cur_s, ssrc_f, sdst_f, ssrc2, sdst2, r2);

    // build the w(r)*C(r) tables (r_full is dead from here on)
    repr_lut_build<<<L_LAYERS * (LUT_T / LROWS), 256, 0, stream>>>(
        offs, widths, fw1, fb1, fw2, fb2, lut);

    repr_embed_h<<<NBLK, 256, 0, stream>>>(
        emb, Z, fc_w, attn_l, attn_r, x, h, el, er);

    for (int l = 0; l < L_LAYERS; l++) {
        repr_alpha<<<(N_NODES * 16 + 255) / 256, 256, 0, stream>>>(
            ssrc_f, rowptr, el, er, md, agg);
        repr_msg_lut<<<N_EDGES / TILE, 256, 0, stream>>>(
            ssrc2, sdst2, r2, ecS, el, er, md, h,
            lut + (size_t)l * LUT_T * HD, agg);
        if (l < L_LAYERS - 1) {
            repr_mlp_h<<<NBLK, 256, 0, stream>>>(
                agg, mw1 + (size_t)l * 128 * 64, mb1 + l * 64,
                mw2 + (size_t)l * 64 * 64, mb2 + l * 64,
                fc_w + (size_t)(l + 1) * 64 * 128, attn_l + (l + 1) * 128,
                attn_r + (l + 1) * 128, x, h, el, er);
        } else {
            repr_mlp_out<<<NBLK, 256, 0, stream>>>(
                agg, mw1 + (size_t)l * 128 * 64, mb1 + l * 64,
                mw2 + (size_t)l * 64 * 64, mb2 + l * 64,
                ow1, ob1, ow2, ob2, x, hh);
        }
    }
    repr_gsum<<<NCHUNK, 256, 0, stream>>>(hh, gids, (float*)d_out);
}

// Round 2
// 674.523 us; speedup vs baseline: 1.1538x; 1.0467x over previous
//
#include <hip/hip_runtime.h>
#include <stdint.h>

#define N_NODES 50000
#define N_EDGES 800000
#define B_GRAPHS 64
#define D_DIM 64
#define HD 128
#define G_GAUSS 50
#define HID_DIM 128
#define L_LAYERS 3
#define LN2 0.69314718055994530942f
#define PI_OVER_8 0.39269908169872414f
#define NCHUNK 196            // ceil(50000/256)

#define TN 64                 // nodes per node-GEMM block
#define TLD 132               // fp32 LDS leading dim for 128-wide tiles
#define XLD 68                // fp32 LDS leading dim for 64-wide tiles
#define NBLK ((N_NODES + TN - 1) / TN)   // 782

// filter-net lookup table: w(r)*C(r) over r in [0,8), linear interpolation.
// LUT_T=2048 -> lerp error ~7e-5 on gs, far below the bf16 storage error.
#define LUT_T 2048
#define LUT_INV_STEP 256.0f   // LUT_T / 8.0
#define LROWS 8               // table rows built per block

__device__ __forceinline__ float sspf(float x) {
    float ax = fabsf(x);
    return fmaxf(x, 0.f) + __logf(1.f + __expf(-ax)) - LN2;
}
__device__ __forceinline__ unsigned short f2bf(float f) {
    union { float f; unsigned int i; } v; v.f = f;
    unsigned int u = v.i;
    return (unsigned short)((u + 0x7FFFu + ((u >> 16) & 1u)) >> 16);
}

// ------------- one-time: zero counters + zero output -------------
__global__ void repr_prep(int* __restrict__ count_f, int* __restrict__ count_s,
                          float* __restrict__ dout) {
    int i = blockIdx.x * 256 + threadIdx.x;
    if (i < N_NODES) count_f[i] = 0;
    else if (i < 2 * N_NODES) count_s[i - N_NODES] = 0;
    else if (i < 2 * N_NODES + B_GRAPHS) dout[i - 2 * N_NODES] = 0.f;
}

// ------------- one-time: build wc(r) = (ssp(gs@W1+b1)@W2 + b2) * C(r) table -------------
// interleaved bf16: lut[l][i][c] = bf16(wc[i][c]) | bf16(wc[i+1][c])<<16
// built in fp32 with accurate expf/cosf; one uint load covers both lerp rows.
__global__ __launch_bounds__(256) void repr_lut_build(
    const float* __restrict__ offs, const float* __restrict__ widths,
    const float* __restrict__ fw1, const float* __restrict__ fb1,
    const float* __restrict__ fw2, const float* __restrict__ fb2,
    unsigned int* __restrict__ lut)
{
    __shared__ float gs_s[LROWS + 1][G_GAUSS];
    __shared__ float hid_s[LROWS + 1][HID_DIM];
    __shared__ float wc_s[LROWS + 1][HD];
    const int nb = LUT_T / LROWS;            // 256 blocks per layer
    int l = blockIdx.x / nb;
    int i0r = (blockIdx.x % nb) * LROWS;
    int tid = threadIdx.x;
    const float step = 8.0f / LUT_T;

    for (int j = tid; j < (LROWS + 1) * G_GAUSS; j += 256) {
        int r = j / G_GAUSS, k = j - r * G_GAUSS;
        float rr = (i0r + r) * step;
        float wdt = widths[k];
        float dr = rr - offs[k];
        gs_s[r][k] = expf(-0.5f / (wdt * wdt) * dr * dr);
    }
    __syncthreads();

    int c = tid & 127, sub = tid >> 7;
    int rlo = sub * 4;                       // rows 0..4 / 4..8 (row 4 dup, benign)
    {
        const float* W1 = fw1 + (size_t)l * G_GAUSS * HID_DIM + c;
        float acc[5];
        float bb = fb1[l * HID_DIM + c];
        #pragma unroll
        for (int r = 0; r < 5; r++) acc[r] = bb;
        for (int k = 0; k < G_GAUSS; k++) {
            float wv = W1[k * HID_DIM];
            #pragma unroll
            for (int r = 0; r < 5; r++)
                acc[r] = fmaf(gs_s[rlo + r][k], wv, acc[r]);
        }
        #pragma unroll
        for (int r = 0; r < 5; r++) hid_s[rlo + r][c] = sspf(acc[r]);
    }
    __syncthreads();
    {
        const float* W2 = fw2 + (size_t)l * HID_DIM * HD + c;
        float acc[5];
        float bb = fb2[l * HD + c];
        #pragma unroll
        for (int r = 0; r < 5; r++) acc[r] = bb;
        for (int k = 0; k < HID_DIM; k++) {
            float wv = W2[k * HD];
            #pragma unroll
            for (int r = 0; r < 5; r++)
                acc[r] = fmaf(hid_s[rlo + r][k], wv, acc[r]);
        }
        #pragma unroll
        for (int r = 0; r < 5; r++) {
            float rr = (i0r + rlo + r) * step;
            float C = (rr < 8.0f) ? 0.5f * (cosf(rr * PI_OVER_8) + 1.f) : 0.f;
            wc_s[rlo + r][c] = acc[r] * C;
        }
    }
    __syncthreads();
    for (int j = tid; j < LROWS * HD; j += 256) {
        int r = j >> 7, cc = j & 127;
        unsigned int lo = f2bf(wc_s[r][cc]);
        unsigned int hi = f2bf(wc_s[r + 1][cc]);
        lut[((size_t)l * LUT_T + i0r + r) * HD + cc] = lo | (hi << 16);
    }
}

// ------------- histograms (+ store r per edge) -------------
__global__ void repr_hist(const float* __restrict__ R,
                          const int* __restrict__ src, const int* __restrict__ dst,
                          int* __restrict__ count_f, int* __restrict__ count_s,
                          float* __restrict__ r_full) {
    int e = blockIdx.x * blockDim.x + threadIdx.x;
    if (e >= N_EDGES) return;
    int s = src[e], d = dst[e];
    atomicAdd(&count_f[d], 1);
    float dx = R[3*s+0] - R[3*d+0];
    float dy = R[3*s+1] - R[3*d+1];
    float dz = R[3*s+2] - R[3*d+2];
    float r = sqrtf(dx*dx + dy*dy + dz*dz);
    r_full[e] = r;
    if (r < 8.0f) atomicAdd(&count_s[d], 1);
}

// ------------- dual 2-level exclusive scan over 50000 counts -------------
__global__ void repr_scanA2(const int* __restrict__ cntA, int* __restrict__ exclA,
                            int* __restrict__ bsumA,
                            const int* __restrict__ cntB, int* __restrict__ exclB,
                            int* __restrict__ bsumB) {
    __shared__ int tmp[256];
    int t = threadIdx.x, b = blockIdx.x;
    const int* cnt; int* excl; int* bsum; int bb;
    if (b < NCHUNK) { cnt = cntA; excl = exclA; bsum = bsumA; bb = b; }
    else            { cnt = cntB; excl = exclB; bsum = bsumB; bb = b - NCHUNK; }
    int i = bb * 256 + t;
    int v = (i < N_NODES) ? cnt[i] : 0;
    tmp[t] = v; __syncthreads();
    for (int off = 1; off < 256; off <<= 1) {
        int add = (t >= off) ? tmp[t - off] : 0;
        __syncthreads();
        tmp[t] += add;
        __syncthreads();
    }
    if (i < N_NODES) excl[i] = tmp[t] - v;
    if (t == 255) bsum[bb] = tmp[255];
}
__global__ void repr_scanB2(const int* __restrict__ bsumA, int* __restrict__ bprefA,
                            int* __restrict__ ecA,
                            const int* __restrict__ bsumB, int* __restrict__ bprefB,
                            int* __restrict__ ecB) {
    __shared__ int tmp[256];
    const int* bsum = blockIdx.x ? bsumB : bsumA;
    int* bpref = blockIdx.x ? bprefB : bprefA;
    int* ec = blockIdx.x ? ecB : ecA;
    int t = threadIdx.x;
    int v = (t < NCHUNK) ? bsum[t] : 0;
    tmp[t] = v; __syncthreads();
    for (int off = 1; off < 256; off <<= 1) {
        int add = (t >= off) ? tmp[t - off] : 0;
        __syncthreads();
        tmp[t] += add;
        __syncthreads();
    }
    if (t < NCHUNK) bpref[t] = tmp[t] - v;
    if (t == 255) ec[0] = tmp[255];
}
__global__ void repr_scanC2(const int* __restrict__ exclA, const int* __restrict__ bprefA,
                            int* __restrict__ curA, int* __restrict__ rowptr,
                            const int* __restrict__ exclB, const int* __restrict__ bprefB,
                            int* __restrict__ curB) {
    int b = blockIdx.x;
    if (b < NCHUNK) {
        int i = b * 256 + threadIdx.x;
        if (i < N_NODES) { int v = exclA[i] + bprefA[b]; curA[i] = v; rowptr[i] = v; }
    } else {
        int i = (b - NCHUNK) * 256 + threadIdx.x;
        if (i < N_NODES) curB[i] = exclB[i] + bprefB[b - NCHUNK];
    }
}

// ------------- scatter: full dst-sorted list + survivor dst-sorted list -------------
__global__ void repr_scatter(const float* __restrict__ r_full,
                             const int* __restrict__ src, const int* __restrict__ dst,
                             int* __restrict__ cur_f, int* __restrict__ cur_s,
                             int* __restrict__ ssrc_f, int* __restrict__ sdst_f,
                             int* __restrict__ ssrc2, int* __restrict__ sdst2,
                             float* __restrict__ r2) {
    int e = blockIdx.x * blockDim.x + threadIdx.x;
    if (e >= N_EDGES) return;
    int s = src[e], d = dst[e];
    float r = r_full[e];
    int pos = atomicAdd(&cur_f[d], 1);
    ssrc_f[pos] = s; sdst_f[pos] = d;
    if (r < 8.0f) {
        int p2 = atomicAdd(&cur_s[d], 1);
        ssrc2[p2] = s; sdst2[p2] = d; r2[p2] = r;
    }
}

// ================= tiled fp32 node GEMMs (64 nodes / block, 256 threads) =================

__device__ __forceinline__ void load_ssp_agg(int base, int tid,
        const float* __restrict__ agg, float* __restrict__ bufA) {
    int row = tid >> 2;
    int c0 = (tid & 3) << 5;
    const float* ap = agg + (size_t)(base + row) * HD + c0;
    float* tp = bufA + row * TLD + c0;
    #pragma unroll
    for (int j = 0; j < 8; j++) {
        float4 v = *(const float4*)(ap + j * 4);
        tp[j*4+0] = sspf(v.x); tp[j*4+1] = sspf(v.y);
        tp[j*4+2] = sspf(v.z); tp[j*4+3] = sspf(v.w);
    }
}

__device__ __forceinline__ void gemm_mlp(int base, int tid,
        const float* __restrict__ w1, const float* __restrict__ b1,
        const float* __restrict__ w2, const float* __restrict__ b2,
        float* __restrict__ x, float* __restrict__ bufA, float* __restrict__ v1s)
{
    const int rg = tid >> 4, cg = tid & 15;
    const int r0 = rg * 4, c0 = cg * 4;
    float acc[4][4];
    #pragma unroll
    for (int r = 0; r < 4; r++)
        #pragma unroll
        for (int c = 0; c < 4; c++) acc[r][c] = 0.f;
    for (int k0 = 0; k0 < 128; k0 += 4) {
        float av[4][4];
        #pragma unroll
        for (int r = 0; r < 4; r++)
            *(float4*)av[r] = *(const float4*)&bufA[(r0 + r) * TLD + k0];
        #pragma unroll
        for (int kk = 0; kk < 4; kk++) {
            float4 wv = *(const float4*)(w1 + (k0 + kk) * 64 + c0);
            float wf[4] = {wv.x, wv.y, wv.z, wv.w};
            #pragma unroll
            for (int r = 0; r < 4; r++)
                #pragma unroll
                for (int c = 0; c < 4; c++)
                    acc[r][c] = fmaf(av[r][kk], wf[c], acc[r][c]);
        }
    }
    {
        float4 bv = *(const float4*)(b1 + c0);
        float ba[4] = {bv.x, bv.y, bv.z, bv.w};
        #pragma unroll
        for (int r = 0; r < 4; r++)
            #pragma unroll
            for (int c = 0; c < 4; c++)
                v1s[(r0 + r) * XLD + c0 + c] = sspf(acc[r][c] + ba[c]);
    }
    __syncthreads();
    float acc2[4][4];
    #pragma unroll
    for (int r = 0; r < 4; r++)
        #pragma unroll
        for (int c = 0; c < 4; c++) acc2[r][c] = 0.f;
    for (int k0 = 0; k0 < 64; k0 += 4) {
        float av[4][4];
        #pragma unroll
        for (int r = 0; r < 4; r++)
            *(float4*)av[r] = *(const float4*)&v1s[(r0 + r) * XLD + k0];
        #pragma unroll
        for (int kk = 0; kk < 4; kk++) {
            float4 wv = *(const float4*)(w2 + (k0 + kk) * 64 + c0);
            float wf[4] = {wv.x, wv.y, wv.z, wv.w};
            #pragma unroll
            for (int r = 0; r < 4; r++)
                #pragma unroll
                for (int c = 0; c < 4; c++)
                    acc2[r][c] = fmaf(av[r][kk], wf[c], acc2[r][c]);
        }
    }
    {
        float4 bv = *(const float4*)(b2 + c0);
        #pragma unroll
        for (int r = 0; r < 4; r++) {
            int n = base + r0 + r;
            float4 xv = *(const float4*)(x + (size_t)n * 64 + c0);
            float4 o;
            o.x = acc2[r][0] + bv.x + xv.x;
            o.y = acc2[r][1] + bv.y + xv.y;
            o.z = acc2[r][2] + bv.z + xv.z;
            o.w = acc2[r][3] + bv.w + xv.w;
            *(float4*)&bufA[(r0 + r) * XLD + c0] = o;
            if (n < N_NODES) *(float4*)(x + (size_t)n * 64 + c0) = o;
        }
    }
    __syncthreads();
}

// h stored packed bf16: hq[n*64 + c/2] = bf16(h[c]) | bf16(h[c+1])<<16
__device__ __forceinline__ void gemm_h(int base, int tid,
        const float* __restrict__ bufA,
        const float* __restrict__ fc_w, const float* __restrict__ attn_l,
        const float* __restrict__ attn_r,
        unsigned int* __restrict__ hq, float* __restrict__ el, float* __restrict__ er)
{
    const int rg = tid >> 4, cg = tid & 15;
    const int r0 = rg * 4, c0 = cg * 8;
    float acc[4][8];
    #pragma unroll
    for (int r = 0; r < 4; r++)
        #pragma unroll
        for (int c = 0; c < 8; c++) acc[r][c] = 0.f;
    for (int k0 = 0; k0 < 64; k0 += 4) {
        float av[4][4];
        #pragma unroll
        for (int r = 0; r < 4; r++)
            *(float4*)av[r] = *(const float4*)&bufA[(r0 + r) * XLD + k0];
        #pragma unroll
        for (int kk = 0; kk < 4; kk++) {
            float4 w0 = *(const float4*)(fc_w + (k0 + kk) * 128 + c0);
            float4 w1v = *(const float4*)(fc_w + (k0 + kk) * 128 + c0 + 4);
            float wf[8] = {w0.x, w0.y, w0.z, w0.w, w1v.x, w1v.y, w1v.z, w1v.w};
            #pragma unroll
            for (int r = 0; r < 4; r++)
                #pragma unroll
                for (int c = 0; c < 8; c++)
                    acc[r][c] = fmaf(av[r][kk], wf[c], acc[r][c]);
        }
    }
    float al[8], ar[8];
    #pragma unroll
    for (int c = 0; c < 8; c++) { al[c] = attn_l[c0 + c]; ar[c] = attn_r[c0 + c]; }
    int head = cg >> 3;
    #pragma unroll
    for (int r = 0; r < 4; r++) {
        int n = base + r0 + r;
        float pel = 0.f, per = 0.f;
        #pragma unroll
        for (int c = 0; c < 8; c++) {
            pel = fmaf(acc[r][c], al[c], pel);
            per = fmaf(acc[r][c], ar[c], per);
        }
        if (n < N_NODES) {
            uint4 pv;
            pv.x = (unsigned int)f2bf(acc[r][0]) | ((unsigned int)f2bf(acc[r][1]) << 16);
            pv.y = (unsigned int)f2bf(acc[r][2]) | ((unsigned int)f2bf(acc[r][3]) << 16);
            pv.z = (unsigned int)f2bf(acc[r][4]) | ((unsigned int)f2bf(acc[r][5]) << 16);
            pv.w = (unsigned int)f2bf(acc[r][6]) | ((unsigned int)f2bf(acc[r][7]) << 16);
            *(uint4*)(hq + (size_t)n * 64 + cg * 4) = pv;
        }
        #pragma unroll
        for (int off = 1; off < 8; off <<= 1) {
            pel += __shfl_xor(pel, off, 64);
            per += __shfl_xor(per, off, 64);
        }
        if ((cg & 7) == 0 && n < N_NODES) {
            el[n * 2 + head] = pel;
            er[n * 2 + head] = per;
        }
    }
}

__global__ __launch_bounds__(256) void repr_embed_h(
        const float* __restrict__ emb, const int* __restrict__ Z,
        const float* __restrict__ fc_w, const float* __restrict__ attn_l,
        const float* __restrict__ attn_r,
        float* __restrict__ x, unsigned int* __restrict__ hq,
        float* __restrict__ el, float* __restrict__ er) {
    __shared__ float bufA[TN * XLD];
    int base = blockIdx.x * TN, tid = threadIdx.x;
    int row = tid >> 2;
    int c0 = (tid & 3) << 4;
    int n = base + row;
    int z = (n < N_NODES) ? Z[n] : 0;
    const float* ep = emb + (size_t)z * D_DIM + c0;
    float* bp = bufA + row * XLD + c0;
    #pragma unroll
    for (int j = 0; j < 4; j++) {
        float4 v = *(const float4*)(ep + j * 4);
        *(float4*)(bp + j * 4) = v;
        if (n < N_NODES) *(float4*)(x + (size_t)n * D_DIM + c0 + j * 4) = v;
    }
    __syncthreads();
    gemm_h(base, tid, bufA, fc_w, attn_l, attn_r, hq, el, er);
}

__global__ __launch_bounds__(256) void repr_mlp_h(
        const float* __restrict__ agg,
        const float* __restrict__ w1, const float* __restrict__ b1,
        const float* __restrict__ w2, const float* __restrict__ b2,
        const float* __restrict__ fc_w, const float* __restrict__ attn_l,
        const float* __restrict__ attn_r,
        float* __restrict__ x, unsigned int* __restrict__ hq,
        float* __restrict__ el, float* __restrict__ er) {
    __shared__ float bufA[TN * TLD];
    __shared__ float v1s[TN * XLD];
    int base = blockIdx.x * TN, tid = threadIdx.x;
    load_ssp_agg(base, tid, agg, bufA);
    __syncthreads();
    gemm_mlp(base, tid, w1, b1, w2, b2, x, bufA, v1s);
    gemm_h(base, tid, bufA, fc_w, attn_l, attn_r, hq, el, er);
}

__global__ __launch_bounds__(256) void repr_mlp_out(
        const float* __restrict__ agg,
        const float* __restrict__ w1, const float* __restrict__ b1,
        const float* __restrict__ w2, const float* __restrict__ b2,
        const float* __restrict__ ow1, const float* __restrict__ ob1,
        const float* __restrict__ ow2, const float* __restrict__ ob2,
        float* __restrict__ x, float* __restrict__ hh) {
    __shared__ float bufA[TN * TLD];
    __shared__ float v1s[TN * XLD];
    int base = blockIdx.x * TN, tid = threadIdx.x;
    load_ssp_agg(base, tid, agg, bufA);
    __syncthreads();
    gemm_mlp(base, tid, w1, b1, w2, b2, x, bufA, v1s);
    const int rg = tid >> 4, cg = tid & 15;
    const int r0 = rg * 4, c0 = cg * 8;
    float acc[4][8];
    #pragma unroll
    for (int r = 0; r < 4; r++)
        #pragma unroll
        for (int c = 0; c < 8; c++) acc[r][c] = 0.f;
    for (int k0 = 0; k0 < 64; k0 += 4) {
        float av[4][4];
        #pragma unroll
        for (int r = 0; r < 4; r++)
            *(float4*)av[r] = *(const float4*)&bufA[(r0 + r) * XLD + k0];
        #pragma unroll
        for (int kk = 0; kk < 4; kk++) {
            float4 w0 = *(const float4*)(ow1 + (k0 + kk) * 128 + c0);
            float4 w1v = *(const float4*)(ow1 + (k0 + kk) * 128 + c0 + 4);
            float wf[8] = {w0.x, w0.y, w0.z, w0.w, w1v.x, w1v.y, w1v.z, w1v.w};
            #pragma unroll
            for (int r = 0; r < 4; r++)
                #pragma unroll
                for (int c = 0; c < 8; c++)
                    acc[r][c] = fmaf(av[r][kk], wf[c], acc[r][c]);
        }
    }
    float o1[8], w2c[8];
    #pragma unroll
    for (int c = 0; c < 8; c++) { o1[c] = ob1[c0 + c]; w2c[c] = ow2[c0 + c]; }
    #pragma unroll
    for (int r = 0; r < 4; r++) {
        int n = base + r0 + r;
        float s = 0.f;
        #pragma unroll
        for (int c = 0; c < 8; c++)
            s = fmaf(sspf(acc[r][c] + o1[c]), w2c[c], s);
        #pragma unroll
        for (int off = 1; off < 16; off <<= 1)
            s += __shfl_xor(s, off, 64);
        if (cg == 0 && n < N_NODES) hh[n] = s + ob2[0];
    }
}

// ------------- softmax denominators (no max subtraction) + agg zeroing -------------
__global__ void repr_alpha(const int* __restrict__ ssrc_f, const int* __restrict__ rowptr,
                           const float* __restrict__ el, const float* __restrict__ er,
                           float2* __restrict__ md, float* __restrict__ agg) {
    int t = blockIdx.x * 256 + threadIdx.x;
    int d = t >> 4;
    int lane16 = t & 15;
    if (d >= N_NODES) return;
    float4 z = make_float4(0.f, 0.f, 0.f, 0.f);
    float4* ar = (float4*)(agg + (size_t)d * HD);
    ar[lane16 * 2] = z;
    ar[lane16 * 2 + 1] = z;
    int rs = rowptr[d];
    int re = (d == N_NODES - 1) ? N_EDGES : rowptr[d + 1];
    float2 erd = *(const float2*)&er[2 * d];
    float s0 = 0.f, s1 = 0.f;
    for (int i = rs + lane16; i < re; i += 16) {
        int s = ssrc_f[i];
        float2 a = *(const float2*)&el[2 * s];
        float v0 = a.x + erd.x; v0 = v0 >= 0.f ? v0 : 0.2f * v0;
        float v1 = a.y + erd.y; v1 = v1 >= 0.f ? v1 : 0.2f * v1;
        s0 += __expf(v0);
        s1 += __expf(v1);
    }
    #pragma unroll
    for (int off = 8; off > 0; off >>= 1) {
        s0 += __shfl_xor(s0, off, 64);
        s1 += __shfl_xor(s1, off, 64);
    }
    if (lane16 == 0) md[d] = make_float2(1.f / s0, 1.f / s1);
}

// ------------- LUT-based message + segmented-reduce scatter -------------
// Per edge: lerp wc(r) from the interleaved bf16 table (uint2 = 2 cols, both
// lerp rows), multiply by packed-bf16 h[src] and the per-(edge,head) alpha
// scale, accumulate segmented sums in registers.
// 256 threads = 64 col-pairs x 4 row-subranges of 16 edges.
#define TILE 64
__global__ __launch_bounds__(256) void repr_msg_lut(
    const int* __restrict__ ssrc2, const int* __restrict__ sdst2,
    const float* __restrict__ r2, const int* __restrict__ ecount,
    const float* __restrict__ el, const float* __restrict__ er,
    const float2* __restrict__ md, const unsigned int* __restrict__ hq,
    const unsigned int* __restrict__ lut,
    float* __restrict__ agg)
{
    __shared__ int4 rowinfo[TILE];     // {lut row i0, src, dst, frac bits}
    __shared__ float scl[TILE][2];
    int EC = ecount[0];
    int base = blockIdx.x * TILE;
    if (base >= EC) return;
    int tid = threadIdx.x;
    if (tid < TILE) {
        int i = base + tid;
        int sn = 0, d = -1, i0 = 0;
        float fr = 0.f, sc0 = 0.f, sc1 = 0.f;
        if (i < EC) {
            sn = ssrc2[i]; d = sdst2[i];
            float t = r2[i] * LUT_INV_STEP;
            i0 = (int)t;
            if (i0 > LUT_T - 1) i0 = LUT_T - 1;
            fr = t - (float)i0;
            float2 a = *(const float2*)&el[2 * sn];
            float2 b = *(const float2*)&er[2 * d];
            float2 rd = md[d];
            float v0 = a.x + b.x; v0 = v0 >= 0.f ? v0 : 0.2f * v0;
            float v1 = a.y + b.y; v1 = v1 >= 0.f ? v1 : 0.2f * v1;
            sc0 = __expf(v0) * rd.x;       // C(r) is folded into the table
            sc1 = __expf(v1) * rd.y;
        }
        rowinfo[tid] = make_int4(i0, sn, d, __float_as_int(fr));
        scl[tid][0] = sc0; scl[tid][1] = sc1;
    }
    __syncthreads();
    const int cp = tid & 63;           // col pair: cols 2cp, 2cp+1
    const int sp = tid >> 6;           // row-subrange: rows [sp*16, sp*16+16)
    const int head = cp >> 5;          // cols 0-63 head0, 64-127 head1
    const int lo = sp * 16;
    const uint2* __restrict__ l2p = (const uint2*)lut;
    float sum0 = 0.f, sum1 = 0.f;
    int cur_d = -1;
    int seg_first = 1;                 // current segment started at subrange begin
    #pragma unroll 4
    for (int j = 0; j < 16; j++) {
        int r = lo + j;
        int4 ri = rowinfo[r];          // wave-uniform LDS broadcast
        if (ri.z != cur_d) {
            if (cur_d >= 0) {
                float* ap = &agg[(size_t)cur_d * HD + 2 * cp];
                // segment possibly extends into previous subrange/block -> atomic
                if (seg_first) { atomicAdd(ap, sum0); atomicAdd(ap + 1, sum1); }
                else *(float2*)ap = make_float2(sum0, sum1);
            }
            cur_d = ri.z; sum0 = 0.f; sum1 = 0.f; seg_first = (j == 0);
        }
        if (ri.z >= 0) {
            uint2 tv = l2p[(size_t)ri.x * 64 + cp];
            float fr = __int_as_float(ri.w);
            float wa0 = __uint_as_float(tv.x << 16);
            float wa1 = __uint_as_float(tv.x & 0xFFFF0000u);
            float wb0 = __uint_as_float(tv.y << 16);
            float wb1 = __uint_as_float(tv.y & 0xFFFF0000u);
            unsigned int hv = hq[(size_t)ri.y * 64 + cp];
            float ha = __uint_as_float(hv << 16);
            float hb = __uint_as_float(hv & 0xFFFF0000u);
            float s = scl[r][head];
            float wa = fmaf(fr, wa1 - wa0, wa0);
            float wb = fmaf(fr, wb1 - wb0, wb0);
            sum0 = fmaf(wa * ha, s, sum0);
            sum1 = fmaf(wb * hb, s, sum1);
        }
    }
    // trailing segment may continue into next subrange/block -> atomic
    if (cur_d >= 0) {
        float* ap = &agg[(size_t)cur_d * HD + 2 * cp];
        atomicAdd(ap, sum0); atomicAdd(ap + 1, sum1);
    }
}

// ------------- graph segment-sum with LDS privatization -> d_out directly -------------
__global__ void repr_gsum(const float* __restrict__ hh, const int* __restrict__ gids,
                          float* __restrict__ dout) {
    __shared__ float bins[B_GRAPHS];
    int t = threadIdx.x;
    if (t < B_GRAPHS) bins[t] = 0.f;
    __syncthreads();
    int i = blockIdx.x * 256 + t;
    if (i < N_NODES) atomicAdd(&bins[gids[i]], hh[i]);
    __syncthreads();
    if (t < B_GRAPHS && bins[t] != 0.f) atomicAdd(&dout[t], bins[t]);
}

extern "C" void kernel_launch(void* const* d_in, const int* in_sizes, int n_in,
                              void* d_out, int out_size, void* d_ws, size_t ws_size,
                              hipStream_t stream) {
    (void)in_sizes; (void)n_in; (void)out_size; (void)ws_size;
    const float* R      = (const float*)d_in[0];
    const int*   Z      = (const int*)d_in[1];
    const int*   src    = (const int*)d_in[2];
    const int*   dst    = (const int*)d_in[3];
    const int*   gids   = (const int*)d_in[4];
    const float* emb    = (const float*)d_in[5];
    const float* offs   = (const float*)d_in[6];
    const float* widths = (const float*)d_in[7];
    const float* fc_w   = (const float*)d_in[8];
    const float* attn_l = (const float*)d_in[9];
    const float* attn_r = (const float*)d_in[10];
    const float* fw1    = (const float*)d_in[11];
    const float* fb1    = (const float*)d_in[12];
    const float* fw2    = (const float*)d_in[13];
    const float* fb2    = (const float*)d_in[14];
    const float* mw1    = (const float*)d_in[15];
    const float* mb1    = (const float*)d_in[16];
    const float* mw2    = (const float*)d_in[17];
    const float* mb2    = (const float*)d_in[18];
    const float* ow1    = (const float*)d_in[19];
    const float* ob1    = (const float*)d_in[20];
    const float* ow2    = (const float*)d_in[21];
    const float* ob2    = (const float*)d_in[22];

    char* p = (char*)d_ws;
    float* x      = (float*)p; p += (size_t)N_NODES * 64 * 4;
    unsigned int* hq = (unsigned int*)p; p += (size_t)N_NODES * 64 * 4;  // packed bf16 pairs
    float* el     = (float*)p; p += (size_t)N_NODES * 2 * 4;
    float* er     = (float*)p; p += (size_t)N_NODES * 2 * 4;
    float2* md    = (float2*)p; p += (size_t)N_NODES * 8;
    float* agg    = (float*)p; p += (size_t)N_NODES * 128 * 4;
    int*   ssrc_f = (int*)p;   p += (size_t)N_EDGES * 4;
    int*   sdst_f = (int*)p;   p += (size_t)N_EDGES * 4;
    int*   rowptr = (int*)p;   p += (size_t)N_NODES * 4;
    int*   ssrc2  = (int*)p;   p += (size_t)N_EDGES * 4;
    int*   sdst2  = (int*)p;   p += (size_t)N_EDGES * 4;
    float* r2     = (float*)p; p += (size_t)N_EDGES * 4;
    float* r_full = (float*)p; p += (size_t)N_EDGES * 4;
    float* hh     = (float*)p; p += (size_t)N_NODES * 4;
    int*   bsumA  = (int*)p;   p += 1024;
    int*   bprefA = (int*)p;   p += 1024;
    int*   bsumB  = (int*)p;   p += 1024;
    int*   bprefB = (int*)p;   p += 1024;
    int*   ecF    = (int*)p;   p += 256;
    int*   ecS    = (int*)p;   p += 256;
    // filter-net LUT aliases r_full: 3*2048*128*4 = 3,145,728 B <= 3,200,000 B.
    // r_full is dead after repr_scatter; lut is built strictly after it.
    unsigned int* lut = (unsigned int*)r_full;
    // scan temporaries aliased into x (x written by repr_embed_h, strictly after
    // repr_scatter in stream order):
    int* count_f = (int*)x;
    int* excl_f  = (int*)((char*)x + 256 * 1024);
    int* cur_f   = (int*)((char*)x + 512 * 1024);
    int* count_s = (int*)((char*)x + 768 * 1024);
    int* excl_s  = (int*)((char*)x + 1024 * 1024);
    int* cur_s   = (int*)((char*)x + 1280 * 1024);

    // one-time prep: zero counters + zero d_out
    repr_prep<<<(2 * N_NODES + B_GRAPHS + 255) / 256, 256, 0, stream>>>(
        count_f, count_s, (float*)d_out);
    repr_hist<<<N_EDGES / 256, 256, 0, stream>>>(R, src, dst, count_f, count_s, r_full);
    repr_scanA2<<<2 * NCHUNK, 256, 0, stream>>>(count_f, excl_f, bsumA,
                                                count_s, excl_s, bsumB);
    repr_scanB2<<<2, 256, 0, stream>>>(bsumA, bprefA, ecF, bsumB, bprefB, ecS);
    repr_scanC2<<<2 * NCHUNK, 256, 0, stream>>>(excl_f, bprefA, cur_f, rowptr,
                                                excl_s, bprefB, cur_s);
    repr_scatter<<<N_EDGES / 256, 256, 0, stream>>>(
        r_full, src, dst, cur_f, cur_s, ssrc_f, sdst_f, ssrc2, sdst2, r2);

    // build the w(r)*C(r) tables (r_full is dead from here on)
    repr_lut_build<<<L_LAYERS * (LUT_T / LROWS), 256, 0, stream>>>(
        offs, widths, fw1, fb1, fw2, fb2, lut);

    repr_embed_h<<<NBLK, 256, 0, stream>>>(
        emb, Z, fc_w, attn_l, attn_r, x, hq, el, er);

    for (int l = 0; l < L_LAYERS; l++) {
        repr_alpha<<<(N_NODES * 16 + 255) / 256, 256, 0, stream>>>(
            ssrc_f, rowptr, el, er, md, agg);
        repr_msg_lut<<<N_EDGES / TILE, 256, 0, stream>>>(
            ssrc2, sdst2, r2, ecS, el, er, md, hq,
            lut + (size_t)l * LUT_T * HD, agg);
        if (l < L_LAYERS - 1) {
            repr_mlp_h<<<NBLK, 256, 0, stream>>>(
                agg, mw1 + (size_t)l * 128 * 64, mb1 + l * 64,
                mw2 + (size_t)l * 64 * 64, mb2 + l * 64,
                fc_w + (size_t)(l + 1) * 64 * 128, attn_l + (l + 1) * 128,
                attn_r + (l + 1) * 128, x, hq, el, er);
        } else {
            repr_mlp_out<<<NBLK, 256, 0, stream>>>(
                agg, mw1 + (size_t)l * 128 * 64, mb1 + l * 64,
                mw2 + (size_t)l * 64 * 64, mb2 + l * 64,
                ow1, ob1, ow2, ob2, x, hh);
        }
    }
    repr_gsum<<<NCHUNK, 256, 0, stream>>>(hh, gids, (float*)d_out);
}